// Round 10
// baseline (318.978 us; speedup 1.0000x reference)
//
#include <hip/hip_runtime.h>
#include <hip/hip_bf16.h>
#include <hip/hip_fp16.h>

typedef float v4 __attribute__((ext_vector_type(4)));
typedef _Float16 hv8 __attribute__((ext_vector_type(8)));
typedef _Float16 h2 __attribute__((ext_vector_type(2)));
typedef unsigned int u32x4 __attribute__((ext_vector_type(4)));
typedef unsigned short u16x4 __attribute__((ext_vector_type(4)));

#define BSHIFT 12
#define NBINS  13          // ceil(50000 / 4096)
#define BINCAP 81920       // per-bin edge capacity (mean ~65k, 60+ sigma headroom)

__device__ __forceinline__ unsigned short f2h(float f) {
    _Float16 h = (_Float16)f;
    return __builtin_bit_cast(unsigned short, h);
}
__device__ __forceinline__ void unph8(uint4 u, v4& lo, v4& hi) {
    h2 a = __builtin_bit_cast(h2, u.x);
    h2 b = __builtin_bit_cast(h2, u.y);
    h2 c = __builtin_bit_cast(h2, u.z);
    h2 d = __builtin_bit_cast(h2, u.w);
    lo[0] = (float)a[0]; lo[1] = (float)a[1]; lo[2] = (float)b[0]; lo[3] = (float)b[1];
    hi[0] = (float)c[0]; hi[1] = (float)c[1]; hi[2] = (float)d[0]; hi[3] = (float)d[1];
}
__device__ __forceinline__ float leaky02(float x) { return x >= 0.f ? x : 0.2f * x; }

// ---- prep: X->f16, W1T/W2T f16, v = W1·att (fp32), counts/cursor/binCursor init ----

__global__ __launch_bounds__(256) void conv_init_kernel(
    const float* __restrict__ X, const float* __restrict__ W1, const float* __restrict__ W2,
    const float* __restrict__ as1, const float* __restrict__ ad1,
    unsigned short* __restrict__ Xh, unsigned short* __restrict__ W1T,
    unsigned short* __restrict__ W2T, float* __restrict__ vsrc, float* __restrict__ vdst,
    int* __restrict__ counts, int* __restrict__ cursor, int* __restrict__ binCursor,
    int XB, int NX, int N, int IB)
{
    int b = blockIdx.x, t = threadIdx.x;
    if (b < XB) {
        int i = (b * 256 + t) * 8;
        if (i < NX) {
            float4 a = *(const float4*)&X[i];
            float4 c = *(const float4*)&X[i + 4];
            ushort4 r0; r0.x = f2h(a.x); r0.y = f2h(a.y); r0.z = f2h(a.z); r0.w = f2h(a.w);
            ushort4 r1; r1.x = f2h(c.x); r1.y = f2h(c.y); r1.z = f2h(c.z); r1.w = f2h(c.w);
            *(ushort4*)&Xh[i] = r0;
            *(ushort4*)&Xh[i + 4] = r1;
        }
    } else if (b < XB + 64) {
        int id = (b - XB) * 256 + t;      // [256 out][64 k]
        int j = id >> 6, k = id & 63;
        W1T[id] = f2h(W1[k * 256 + j]);
    } else if (b < XB + 64 + 128) {
        int id = (b - XB - 64) * 256 + t; // [128 out][256 k]
        int j = id >> 8, k = id & 255;
        W2T[id] = f2h(W2[k * 128 + j]);
    } else if (b < XB + 64 + 128 + IB) {
        int i = (b - XB - 64 - 128) * 256 + t;
        if (i < N) { counts[i] = 1; cursor[i] = 1; }   // slot 0 reserved for self-loop
    } else {
        int vb = b - (XB + 64 + 128 + IB);
        if (vb == 0 && t < 16) binCursor[t] = 0;
        const float* att = vb ? ad1 : as1;
        float* vout = vb ? vdst : vsrc;
        int h = t >> 6, k = t & 63;
        float s = 0.f;
        const float* wrow = &W1[k * 256 + h * 64];
        const float* arow = &att[h * 64];
        #pragma unroll 8
        for (int c = 0; c < 64; c++) s += wrow[c] * arow[c];
        vout[t] = s;
    }
}

// ---------------- CSR build (degree padded to multiple of 8) ----------------

__global__ __launch_bounds__(256) void hist_kernel(const int* __restrict__ dst, int* counts, int E) {
    int e = blockIdx.x * 256 + threadIdx.x;
    if (e < E) atomicAdd(&counts[dst[e]], 1);
}

__global__ __launch_bounds__(256) void scanA_kernel(const int* __restrict__ counts,
                                                    int* __restrict__ blockSums, int n) {
    __shared__ int red[256];
    int b = blockIdx.x, t = threadIdx.x;
    int base = b * 1024;
    int s = 0;
    #pragma unroll
    for (int j = 0; j < 4; j++) {
        int i = base + j * 256 + t;
        if (i < n) s += (counts[i] + 7) & ~7;
    }
    red[t] = s; __syncthreads();
    for (int off = 128; off; off >>= 1) { if (t < off) red[t] += red[t + off]; __syncthreads(); }
    if (t == 0) blockSums[b] = red[0];
}

// scanC: offsets + self-loop slot + pad fill
__global__ __launch_bounds__(256) void scanC_kernel(const int* __restrict__ counts,
                                                    const int* __restrict__ blockSums,
                                                    int* __restrict__ offsets,
                                                    int* __restrict__ csr_src, int n, int nb) {
    __shared__ int red[256];
    __shared__ int base_s;
    int b = blockIdx.x, t = threadIdx.x;
    if (t < 64) {
        int v = (t < nb) ? blockSums[t] : 0;
        #pragma unroll
        for (int off = 1; off < 64; off <<= 1) {
            int u = __shfl_up(v, off);
            if (t >= off) v += u;
        }
        int basev = (b == 0) ? 0 : __shfl(v, b - 1);
        int tot = __shfl(v, nb - 1);
        if (t == 0) {
            base_s = basev;
            if (b == 0) offsets[n] = tot;
        }
    }
    int base = b * 1024;
    int c[4], cn[4]; int s = 0;
    #pragma unroll
    for (int j = 0; j < 4; j++) {
        int i = base + t * 4 + j;
        cn[j] = (i < n) ? counts[i] : 0;
        c[j] = (cn[j] + 7) & ~7;
        s += c[j];
    }
    red[t] = s; __syncthreads();
    for (int off = 1; off < 256; off <<= 1) {
        int u = (t >= off) ? red[t - off] : 0;
        __syncthreads();
        red[t] += u;
        __syncthreads();
    }
    int excl = red[t] - s + base_s;
    #pragma unroll
    for (int j = 0; j < 4; j++) {
        int i = base + t * 4 + j;
        if (i < n) {
            offsets[i] = excl;
            csr_src[excl] = i;                                  // self-loop at slot 0
            for (int q = cn[j]; q < c[j]; q++) csr_src[excl + q] = i;  // pads (w masked 0)
        }
        excl += c[j];
    }
}

// ---------------- pass 1: bin edges by dst>>12 with LDS staging ----------------
// one 2048-edge chunk per block; LDS ordinal assignment -> run reservation ->
// LDS-ordered copy-out (coalesced runs into binBuf).

__global__ __launch_bounds__(256) void bin1_kernel(
    const int* __restrict__ src, const int* __restrict__ dst,
    int* __restrict__ binCursor, int2* __restrict__ binBuf, int E)
{
    __shared__ int cnt[NBINS], lbase[NBINS], gbase[NBINS];
    __shared__ int2 staged[2048];
    int t = threadIdx.x;
    int e0 = blockIdx.x * 2048;
    if (t < NBINS) cnt[t] = 0;
    __syncthreads();

    int mySrc[8], myDst[8], myBin[8], myOrd[8];
    #pragma unroll
    for (int k = 0; k < 8; k++) {
        int id = e0 + k * 256 + t;
        bool v = id < E;
        int d = v ? dst[id] : 0;
        mySrc[k] = v ? src[id] : 0;
        myDst[k] = d;
        myBin[k] = d >> BSHIFT;
        myOrd[k] = v ? atomicAdd(&cnt[myBin[k]], 1) : -1;
    }
    __syncthreads();
    if (t == 0) {
        int run = 0;
        for (int j = 0; j < NBINS; j++) { lbase[j] = run; run += cnt[j]; }
    }
    __syncthreads();
    if (t < NBINS) gbase[t] = (cnt[t] > 0) ? atomicAdd(&binCursor[t], cnt[t]) : 0;
    #pragma unroll
    for (int k = 0; k < 8; k++)
        if (myOrd[k] >= 0) staged[lbase[myBin[k]] + myOrd[k]] = make_int2(mySrc[k], myDst[k]);
    __syncthreads();
    int total = lbase[NBINS - 1] + cnt[NBINS - 1];
    for (int i = t; i < total; i += 256) {
        int j = 0;
        #pragma unroll
        for (int q = 1; q < NBINS; q++) if (i >= lbase[q]) j = q;
        binBuf[(size_t)j * BINCAP + gbase[j] + (i - lbase[j])] = staged[i];
    }
}

// ---------------- pass 2: place bin edges into CSR (XCD-pinned bins) ----------------
// block b: slot s=b&7, chunk c=b>>3; bins j ≡ s (mod 8) -> same XCD (if round-robin),
// so each bin's csr_src region assembles full lines in one L2.

__global__ __launch_bounds__(256) void bin2_kernel(
    const int2* __restrict__ binBuf, const int* __restrict__ binCursor,
    const int* __restrict__ offsets, int* __restrict__ cursor, int* __restrict__ csr_src)
{
    int t = threadIdx.x;
    int s = blockIdx.x & 7;
    int c = blockIdx.x >> 3;
    for (int j = s; j < NBINS; j += 8) {
        int cnt = binCursor[j];
        int base = c * 1024;
        if (base >= cnt) continue;
        const int2* buf = binBuf + (size_t)j * BINCAP;
        #pragma unroll
        for (int k = 0; k < 4; k++) {
            int i = base + k * 256 + t;
            if (i < cnt) {
                int2 e = buf[i];
                int pos = offsets[e.y] + atomicAdd(&cursor[e.y], 1);
                csr_src[pos] = e.x;
            }
        }
    }
}

// ---------------- attention dots: a_src1/a_dst1 = Xh · v ----------------

__global__ __launch_bounds__(256) void attdot_kernel(
    const unsigned short* __restrict__ Xh, const float* __restrict__ vsrc,
    const float* __restrict__ vdst, float* __restrict__ a_src1, float* __restrict__ a_dst1,
    int N)
{
    __shared__ float vs[256], vd[256];
    int t = threadIdx.x;
    vs[t] = vsrc[t]; vd[t] = vdst[t];
    __syncthreads();
    int w = t >> 6, lane = t & 63;
    int nd = lane >> 3, sub = lane & 7, kc = sub * 8;
    int node = blockIdx.x * 32 + w * 8 + nd;
    if (node >= N) node = N - 1;
    uint4 x = *(const uint4*)&Xh[(size_t)node * 64 + kc];
    v4 lo, hi; unph8(x, lo, hi);
    float ps[4], pd[4];
    #pragma unroll
    for (int h = 0; h < 4; h++) {
        float s = 0.f, d = 0.f;
        #pragma unroll
        for (int j = 0; j < 4; j++) {
            s += lo[j] * vs[h * 64 + kc + j];     d += lo[j] * vd[h * 64 + kc + j];
            s += hi[j] * vs[h * 64 + kc + 4 + j]; d += hi[j] * vd[h * 64 + kc + 4 + j];
        }
        ps[h] = s; pd[h] = d;
    }
    #pragma unroll
    for (int off = 1; off < 8; off <<= 1)
        #pragma unroll
        for (int h = 0; h < 4; h++) {
            ps[h] += __shfl_xor(ps[h], off);
            pd[h] += __shfl_xor(pd[h], off);
        }
    if (sub == 0) {
        v4 o0; o0[0] = ps[0]; o0[1] = ps[1]; o0[2] = ps[2]; o0[3] = ps[3];
        v4 o1; o1[0] = pd[0]; o1[1] = pd[1]; o1[2] = pd[2]; o1[3] = pd[3];
        *(v4*)&a_src1[node * 4] = o0;
        *(v4*)&a_dst1[node * 4] = o1;
    }
}

// ---------------- Layer 1 fused softmax + X-aggregation ----------------

__global__ __launch_bounds__(256) void aggX_kernel(
    const int* __restrict__ offsets, const int* __restrict__ counts,
    const int* __restrict__ csr_src,
    const float* __restrict__ a_src1, const float* __restrict__ a_dst1,
    const unsigned short* __restrict__ Xh, unsigned short* __restrict__ Xagg, int N)
{
    int wid  = threadIdx.x >> 6;
    int lane = threadIdx.x & 63;
    int nd = lane >> 5;
    int p = (lane >> 3) & 3, sub = lane & 7, kc = sub * 8;
    int n = blockIdx.x * 8 + wid * 2 + nd;
    if (n >= N) return;
    int beg   = offsets[n];
    int cnt   = counts[n];
    int steps = (offsets[n + 1] - beg) >> 2;
    v4 adst = *(const v4*)&a_dst1[n * 4];

    v4 accL[4], accH[4];
    #pragma unroll
    for (int h = 0; h < 4; h++) { accL[h] = (v4)0.f; accH[h] = (v4)0.f; }
    v4 den = (v4)0.f;

    int s0, s1, s2;
    uint4 x0, x1;
    v4 a0, a1;

    s0 = __builtin_nontemporal_load(&csr_src[beg + p]);
    s1 = __builtin_nontemporal_load(&csr_src[beg + 4 + p]);
    x0 = *(const uint4*)&Xh[(size_t)s0 * 64 + kc];
    a0 = *(const v4*)&a_src1[s0 * 4];

    for (int i = 0; i < steps; i++) {
        int i2 = (i + 2 < steps) ? i + 2 : steps - 1;
        s2 = __builtin_nontemporal_load(&csr_src[beg + i2 * 4 + p]);
        if (i + 1 < steps) {
            x1 = *(const uint4*)&Xh[(size_t)s1 * 64 + kc];
            a1 = *(const v4*)&a_src1[s1 * 4];
        }
        bool valid = (i * 4 + p) < cnt;
        v4 lo, hi; unph8(x0, lo, hi);
        #pragma unroll
        for (int h = 0; h < 4; h++) {
            float e = fminf(leaky02(a0[h] + adst[h]), 80.f);
            float w = valid ? __expf(e) : 0.f;
            den[h] += w;
            accL[h] += w * lo;
            accH[h] += w * hi;
        }
        x0 = x1; a0 = a1; s1 = s2;
    }

    #pragma unroll
    for (int off = 8; off < 32; off <<= 1) {
        #pragma unroll
        for (int h = 0; h < 4; h++) {
            den[h] += __shfl_xor(den[h], off);
            #pragma unroll
            for (int c = 0; c < 4; c++) {
                accL[h][c] += __shfl_xor(accL[h][c], off);
                accH[h][c] += __shfl_xor(accH[h][c], off);
            }
        }
    }
    if (p == 0) {
        #pragma unroll
        for (int h = 0; h < 4; h++) {
            float inv = 1.f / den[h];
            v4 oL = accL[h] * inv, oH = accH[h] * inv;
            u32x4 pk;
            pk[0] = (unsigned)f2h(oL[0]) | ((unsigned)f2h(oL[1]) << 16);
            pk[1] = (unsigned)f2h(oL[2]) | ((unsigned)f2h(oL[3]) << 16);
            pk[2] = (unsigned)f2h(oH[0]) | ((unsigned)f2h(oH[1]) << 16);
            pk[3] = (unsigned)f2h(oH[2]) | ((unsigned)f2h(oH[3]) << 16);
            __builtin_nontemporal_store(pk, (u32x4*)&Xagg[(size_t)n * 256 + h * 64 + kc]);
        }
    }
}

// ---------------- H = Xagg (per-head) · W1 + b1, f16 out ----------------

__global__ __launch_bounds__(256) void gemmH_kernel(
    const unsigned short* __restrict__ Xagg, const unsigned short* __restrict__ W1T,
    const float* __restrict__ b1, unsigned short* __restrict__ Hh, int N)
{
    __shared__ unsigned short As[32 * 264];
    __shared__ unsigned short Bs[256 * 72];
    int t  = threadIdx.x;
    int n0 = blockIdx.x * 32;

    #pragma unroll
    for (int c = 0; c < 4; c++) {
        int idx = c * 256 + t;
        int row = idx >> 5, seg = idx & 31;
        int gr = n0 + row; if (gr >= N) gr = N - 1;
        *(uint4*)&As[row * 264 + seg * 8] = *(const uint4*)&Xagg[(size_t)gr * 256 + seg * 8];
    }
    #pragma unroll
    for (int c = 0; c < 8; c++) {
        int idx = c * 256 + t;
        int row = idx >> 3, seg = idx & 7;
        *(uint4*)&Bs[row * 72 + seg * 8] = *(const uint4*)&W1T[row * 64 + seg * 8];
    }
    __syncthreads();

    int w = t >> 6, l = t & 63;
    int nh = w & 1, th = w >> 1;
    int quad = l >> 4, lm = l & 15;
    int node = n0 + nh * 16 + lm;

    hv8 xf0[2], xf1[2];
    #pragma unroll
    for (int hh = 0; hh < 2; hh++) {
        int h = th * 2 + hh;
        xf0[hh] = *(const hv8*)&As[(nh * 16 + lm) * 264 + h * 64 + quad * 8];
        xf1[hh] = *(const hv8*)&As[(nh * 16 + lm) * 264 + h * 64 + 32 + quad * 8];
    }
    #pragma unroll
    for (int tt2 = 0; tt2 < 8; tt2++) {
        int tt = th * 8 + tt2;
        int hh = tt2 >> 2;
        hv8 wf0 = *(const hv8*)&Bs[(tt * 16 + lm) * 72 + quad * 8];
        hv8 wf1 = *(const hv8*)&Bs[(tt * 16 + lm) * 72 + 32 + quad * 8];
        v4 a = (v4)0.f;
        a = __builtin_amdgcn_mfma_f32_16x16x32_f16(wf0, xf0[hh], a, 0, 0, 0);
        a = __builtin_amdgcn_mfma_f32_16x16x32_f16(wf1, xf1[hh], a, 0, 0, 0);
        int ch = tt * 16 + quad * 4;
        v4 bias = *(const v4*)&b1[ch];
        v4 o = a + bias;
        if (node < N) {
            u16x4 b;
            b[0] = f2h(o[0]); b[1] = f2h(o[1]); b[2] = f2h(o[2]); b[3] = f2h(o[3]);
            __builtin_nontemporal_store(b, (u16x4*)&Hh[(size_t)node * 256 + ch]);
        }
    }
}

// ---------------- Layer 2 GEMM via MFMA (f16) + attention dots ----------------

__global__ __launch_bounds__(256) void gemm2_mfma_kernel(
    const unsigned short* __restrict__ Hh, const unsigned short* __restrict__ W2T,
    const float* __restrict__ att_src, const float* __restrict__ att_dst,
    unsigned short* __restrict__ xh2, float* __restrict__ a_src2, float* __restrict__ a_dst2,
    int N)
{
    __shared__ unsigned short As[64 * 72];
    __shared__ unsigned short Bs[128 * 72];
    int t  = threadIdx.x;
    int n0 = blockIdx.x * 64;
    int w = t >> 6, l = t & 63;
    int quad = l >> 4, lm = l & 15;

    v4 acc[8];
    #pragma unroll
    for (int tt = 0; tt < 8; tt++) acc[tt] = (v4)0.f;

    for (int kt = 0; kt < 256; kt += 64) {
        __syncthreads();
        #pragma unroll
        for (int c = 0; c < 2; c++) {
            int idx = c * 256 + t;
            int row = idx >> 3, seg = idx & 7;
            int gr = n0 + row; if (gr >= N) gr = N - 1;
            *(uint4*)&As[row * 72 + seg * 8] = *(const uint4*)&Hh[(size_t)gr * 256 + kt + seg * 8];
        }
        #pragma unroll
        for (int c = 0; c < 4; c++) {
            int idx = c * 256 + t;
            int row = idx >> 3, seg = idx & 7;
            *(uint4*)&Bs[row * 72 + seg * 8] = *(const uint4*)&W2T[row * 256 + kt + seg * 8];
        }
        __syncthreads();

        hv8 xf0 = *(const hv8*)&As[(w * 16 + lm) * 72 + quad * 8];
        hv8 xf1 = *(const hv8*)&As[(w * 16 + lm) * 72 + 32 + quad * 8];
        #pragma unroll
        for (int tt = 0; tt < 8; tt++) {
            hv8 wf0 = *(const hv8*)&Bs[(tt * 16 + lm) * 72 + quad * 8];
            hv8 wf1 = *(const hv8*)&Bs[(tt * 16 + lm) * 72 + 32 + quad * 8];
            acc[tt] = __builtin_amdgcn_mfma_f32_16x16x32_f16(wf0, xf0, acc[tt], 0, 0, 0);
            acc[tt] = __builtin_amdgcn_mfma_f32_16x16x32_f16(wf1, xf1, acc[tt], 0, 0, 0);
        }
    }

    int node = n0 + w * 16 + lm;
    float vs = 0.f, vd = 0.f;
    #pragma unroll
    for (int tt = 0; tt < 8; tt++) {
        int ch = tt * 16 + quad * 4;
        v4 d = acc[tt];
        v4 as_ = *(const v4*)&att_src[ch];
        v4 ad_ = *(const v4*)&att_dst[ch];
        #pragma unroll
        for (int r = 0; r < 4; r++) { vs += d[r] * as_[r]; vd += d[r] * ad_[r]; }
        ushort4 b; b.x = f2h(d[0]); b.y = f2h(d[1]); b.z = f2h(d[2]); b.w = f2h(d[3]);
        if (node < N) *(ushort4*)&xh2[(size_t)node * 128 + ch] = b;   // cached: gather target
    }
    vs += __shfl_xor(vs, 16); vs += __shfl_xor(vs, 32);
    vd += __shfl_xor(vd, 16); vd += __shfl_xor(vd, 32);
    if (l < 16 && node < N) { a_src2[node] = vs; a_dst2[node] = vd; }
}

// ---------------- Layer 2 fused softmax+aggregation ----------------

__global__ __launch_bounds__(256) void aggf2_kernel(
    const int* __restrict__ offsets, const int* __restrict__ counts,
    const int* __restrict__ csr_src,
    const float* __restrict__ a_src2, const float* __restrict__ a_dst2,
    const unsigned short* __restrict__ xh2, const float* __restrict__ b2,
    float* __restrict__ out, int N)
{
    int wid  = threadIdx.x >> 6;
    int lane = threadIdx.x & 63;
    int nd = lane >> 5;
    int p = (lane >> 4) & 1;
    int c0 = (lane & 15) * 8;
    int n = blockIdx.x * 8 + wid * 2 + nd;
    if (n >= N) return;
    int beg   = offsets[n];
    int cnt   = counts[n];
    int steps = (offsets[n + 1] - beg) >> 1;
    float adst = a_dst2[n];

    v4 accL = (v4)0.f, accH = (v4)0.f;
    float den = 0.f;
    int s0, s1, s2;
    float a0, a1;
    uint4 x0, x1;

    s0 = __builtin_nontemporal_load(&csr_src[beg + p]);
    s1 = __builtin_nontemporal_load(&csr_src[beg + 2 + p]);
    x0 = *(const uint4*)&xh2[(size_t)s0 * 128 + c0];
    a0 = a_src2[s0];

    for (int i = 0; i < steps; i++) {
        int i2 = (i + 2 < steps) ? i + 2 : steps - 1;
        s2 = __builtin_nontemporal_load(&csr_src[beg + i2 * 2 + p]);
        if (i + 1 < steps) {
            x1 = *(const uint4*)&xh2[(size_t)s1 * 128 + c0];
            a1 = a_src2[s1];
        }
        float e = fminf(leaky02(a0 + adst), 80.f);
        float w = ((i * 2 + p) < cnt) ? __expf(e) : 0.f;
        den += w;
        v4 lo, hi; unph8(x0, lo, hi);
        accL += w * lo; accH += w * hi;
        x0 = x1; a0 = a1; s1 = s2;
    }

    den += __shfl_xor(den, 16);
    #pragma unroll
    for (int c = 0; c < 4; c++) {
        accL[c] += __shfl_xor(accL[c], 16);
        accH[c] += __shfl_xor(accH[c], 16);
    }
    if (p == 0) {
        float inv = 1.f / den;
        v4 bl = *(const v4*)&b2[c0];
        v4 bh = *(const v4*)&b2[c0 + 4];
        v4 oL = accL * inv + bl;
        v4 oH = accH * inv + bh;
        __builtin_nontemporal_store(oL, (v4*)&out[(size_t)n * 128 + c0]);
        __builtin_nontemporal_store(oH, (v4*)&out[(size_t)n * 128 + c0 + 4]);
    }
}

// ---------------- launcher ----------------

static inline size_t rnd256(size_t x) { return (x + 255) & ~(size_t)255; }

extern "C" void kernel_launch(void* const* d_in, const int* in_sizes, int n_in,
                              void* d_out, int out_size, void* d_ws, size_t ws_size,
                              hipStream_t stream) {
    const float* X   = (const float*)d_in[0];
    const int*   ei  = (const int*)d_in[1];
    const float* W1  = (const float*)d_in[2];
    const float* as1 = (const float*)d_in[3];
    const float* ad1 = (const float*)d_in[4];
    const float* b1  = (const float*)d_in[5];
    const float* W2  = (const float*)d_in[6];
    const float* as2 = (const float*)d_in[7];
    const float* ad2 = (const float*)d_in[8];
    const float* b2  = (const float*)d_in[9];
    float* out = (float*)d_out;

    const int N = in_sizes[0] / 64;   // 50000
    const int E = in_sizes[1] / 2;    // 800000
    const int* srcArr = ei;
    const int* dstArr = ei + E;
    const size_t CSRMAX = (size_t)E + 8 * (size_t)N;
    const int NB = (N + 1023) / 1024;
    const int XB = (N * 64 / 8 + 255) / 256;
    const int IB = (N + 255) / 256;

    char* w = (char*)d_ws;
    unsigned short* Xh     = (unsigned short*)w;  w += rnd256((size_t)N * 64 * 2);
    unsigned short* W1T    = (unsigned short*)w;  w += rnd256((size_t)256 * 64 * 2);
    unsigned short* W2T    = (unsigned short*)w;  w += rnd256((size_t)128 * 256 * 2);
    float* vsrc    = (float*)w;  w += rnd256(256 * 4);
    float* vdst    = (float*)w;  w += rnd256(256 * 4);
    unsigned short* Xagg   = (unsigned short*)w;  w += rnd256((size_t)N * 256 * 2);
    unsigned short* Hh     = (unsigned short*)w;  w += rnd256((size_t)N * 256 * 2);
    float* a_src1  = (float*)w;  w += rnd256((size_t)N * 4 * 4);
    float* a_dst1  = (float*)w;  w += rnd256((size_t)N * 4 * 4);
    float* a_src2v = (float*)w;  w += rnd256((size_t)N * 4);
    float* a_dst2v = (float*)w;  w += rnd256((size_t)N * 4);
    int*   counts  = (int*)w;    w += rnd256((size_t)N * 4);
    int*   offsets = (int*)w;    w += rnd256((size_t)(N + 1) * 4);
    int*   cursor  = (int*)w;    w += rnd256((size_t)N * 4);
    int*   blockSums = (int*)w;  w += rnd256((size_t)NB * 4);
    int*   binCursor = (int*)w;  w += rnd256(16 * 4);
    int2*  binBuf  = (int2*)w;   w += rnd256((size_t)NBINS * BINCAP * 8);
    int*   csr_src = (int*)w;    w += rnd256(CSRMAX * 4);
    unsigned short* xh2 = Xagg;  // Xagg dead after gemmH; reuse for layer-2 features

    // prep (conv + v-vectors + CSR init fused)
    conv_init_kernel<<<XB + 64 + 128 + IB + 2, 256, 0, stream>>>(
        X, W1, W2, as1, ad1, Xh, W1T, W2T, vsrc, vdst, counts, cursor, binCursor,
        XB, N * 64, N, IB);
    // CSR build: hist -> scan (+self/pad fill) -> binned two-phase scatter
    hist_kernel<<<(E + 255) / 256, 256, 0, stream>>>(dstArr, counts, E);
    scanA_kernel<<<NB, 256, 0, stream>>>(counts, blockSums, N);
    scanC_kernel<<<NB, 256, 0, stream>>>(counts, blockSums, offsets, csr_src, N, NB);
    bin1_kernel<<<(E + 2047) / 2048, 256, 0, stream>>>(srcArr, dstArr, binCursor, binBuf, E);
    bin2_kernel<<<8 * (BINCAP / 1024), 256, 0, stream>>>(binBuf, binCursor, offsets,
                                                         cursor, csr_src);
    // layer 1 (flipped: attdot -> aggregate X -> GEMM)
    attdot_kernel<<<(N + 31) / 32, 256, 0, stream>>>(Xh, vsrc, vdst, a_src1, a_dst1, N);
    aggX_kernel<<<(N + 7) / 8, 256, 0, stream>>>(offsets, counts, csr_src, a_src1, a_dst1,
                                                 Xh, Xagg, N);
    gemmH_kernel<<<(N + 31) / 32, 256, 0, stream>>>(Xagg, W1T, b1, Hh, N);
    // layer 2
    gemm2_mfma_kernel<<<(N + 63) / 64, 256, 0, stream>>>(Hh, W2T, as2, ad2, xh2,
                                                         a_src2v, a_dst2v, N);
    aggf2_kernel<<<(N + 7) / 8, 256, 0, stream>>>(offsets, counts, csr_src, a_src2v, a_dst2v,
                                                  xh2, b2, out, N);
}